// Round 1
// baseline (1090.291 us; speedup 1.0000x reference)
//
#include <hip/hip_runtime.h>

#define N_NODES   100000
#define N_EDGES   1600000
#define NFEAT     128
#define N_GRAPHS  1024

#define SCAN_CHUNK  1024
#define SCAN_BLOCKS ((N_NODES + SCAN_CHUNK - 1) / SCAN_CHUNK)   // 98

// ---------------- init: zero counts + pool accumulators ----------------
__global__ __launch_bounds__(256) void k_init(int* counts, float* gsum, float* gcnt) {
    int i = blockIdx.x * blockDim.x + threadIdx.x;
    if (i < N_NODES) counts[i] = 0;
    if (i < N_GRAPHS) { gsum[i] = 0.f; gcnt[i] = 0.f; }
}

// ---------------- in-degree histogram over dst ----------------
__global__ __launch_bounds__(256) void k_hist(const int* __restrict__ dst, int* counts) {
    int e = blockIdx.x * blockDim.x + threadIdx.x;
    if (e < N_EDGES) atomicAdd(&counts[dst[e]], 1);
}

// ---------------- deg^{-1/2} (self-loop makes deg >= 1) ----------------
__global__ __launch_bounds__(256) void k_dinv(const int* __restrict__ counts, float* dinv) {
    int n = blockIdx.x * blockDim.x + threadIdx.x;
    if (n < N_NODES) dinv[n] = rsqrtf((float)(counts[n] + 1));
}

// ---------------- exclusive scan of counts -> offsets (3 phases) ----------------
__global__ __launch_bounds__(256) void k_scan_partial(const int* __restrict__ counts, int* blockSums) {
    int base = blockIdx.x * SCAN_CHUNK;
    int t = threadIdx.x;
    int s = 0;
    for (int i = t; i < SCAN_CHUNK; i += 256) {
        int idx = base + i;
        if (idx < N_NODES) s += counts[idx];
    }
    for (int d = 32; d > 0; d >>= 1) s += __shfl_down(s, d, 64);
    __shared__ int lds[4];
    int lane = t & 63, w = t >> 6;
    if (lane == 0) lds[w] = s;
    __syncthreads();
    if (t == 0) blockSums[blockIdx.x] = lds[0] + lds[1] + lds[2] + lds[3];
}

__global__ void k_scan_blocksums(int* blockSums, int* blockOffs, int* offsets) {
    int run = 0;
    for (int b = 0; b < SCAN_BLOCKS; ++b) { blockOffs[b] = run; run += blockSums[b]; }
    offsets[N_NODES] = run;   // == N_EDGES
}

__global__ __launch_bounds__(256) void k_scan_final(const int* __restrict__ counts,
                                                    const int* __restrict__ blockOffs,
                                                    int* offsets, int* cursor) {
    int base = blockIdx.x * SCAN_CHUNK;
    int t = threadIdx.x;
    int c[4];
    int ts = 0;
    #pragma unroll
    for (int i = 0; i < 4; ++i) {
        int idx = base + 4 * t + i;
        c[i] = (idx < N_NODES) ? counts[idx] : 0;
        ts += c[i];
    }
    int lane = t & 63, w = t >> 6;
    int inc = ts;
    #pragma unroll
    for (int d = 1; d < 64; d <<= 1) {
        int v = __shfl_up(inc, d, 64);
        if (lane >= d) inc += v;
    }
    __shared__ int wsum[4];
    if (lane == 63) wsum[w] = inc;
    __syncthreads();
    int wpre = 0;
    for (int i = 0; i < w; ++i) wpre += wsum[i];
    int run = blockOffs[blockIdx.x] + wpre + (inc - ts);
    #pragma unroll
    for (int i = 0; i < 4; ++i) {
        int idx = base + 4 * t + i;
        if (idx < N_NODES) { offsets[idx] = run; cursor[idx] = run; }
        run += c[i];
    }
}

// ---------------- CSR fill: col (src idx) + edge weight ----------------
__global__ __launch_bounds__(256) void k_fill(const int* __restrict__ src, const int* __restrict__ dst,
                                              const float* __restrict__ dinv, int* cursor,
                                              int* col, float* wgt) {
    int e = blockIdx.x * blockDim.x + threadIdx.x;
    if (e < N_EDGES) {
        int s = src[e], d = dst[e];
        int p = atomicAdd(&cursor[d], 1);
        col[p] = s;
        wgt[p] = dinv[s] * dinv[d];
    }
}

// ---------------- fp32 GEMM: C[M,128] = A[M,128] @ W[128,128] ----------------
// 32 rows/block, K tiled by 64; LDS 40KB -> 4 blocks/CU.
#define GM 32
#define KB 64
__global__ __launch_bounds__(256) void k_gemm(const float* __restrict__ A,
                                              const float* __restrict__ W,
                                              float* __restrict__ C) {
    __shared__ float sW[KB][NFEAT];   // 32 KB
    __shared__ float sA[GM][KB];      //  8 KB
    int t = threadIdx.x;
    int rowBase = blockIdx.x * GM;
    int tc = t & 31;   // cols 4*tc .. 4*tc+3
    int tr = t >> 5;   // rows 4*tr .. 4*tr+3
    float acc[4][4] = {{0.f}};
    for (int kt = 0; kt < NFEAT; kt += KB) {
        __syncthreads();
        {
            const float4* W4 = (const float4*)(W + (size_t)kt * NFEAT);
            float4* sW4 = (float4*)&sW[0][0];
            for (int i = t; i < KB * NFEAT / 4; i += 256) sW4[i] = W4[i];
        }
        for (int i = t; i < GM * KB / 4; i += 256) {
            int r = i >> 4;          // 16 float4 per 64-col row
            int c4 = i & 15;
            const float4* Ar = (const float4*)(A + (size_t)(rowBase + r) * NFEAT + kt);
            ((float4*)&sA[r][0])[c4] = Ar[c4];
        }
        __syncthreads();
        #pragma unroll 8
        for (int k = 0; k < KB; ++k) {
            float4 wv = *(const float4*)&sW[k][4 * tc];
            float a0 = sA[4 * tr + 0][k];
            float a1 = sA[4 * tr + 1][k];
            float a2 = sA[4 * tr + 2][k];
            float a3 = sA[4 * tr + 3][k];
            acc[0][0] = fmaf(a0, wv.x, acc[0][0]);
            acc[0][1] = fmaf(a0, wv.y, acc[0][1]);
            acc[0][2] = fmaf(a0, wv.z, acc[0][2]);
            acc[0][3] = fmaf(a0, wv.w, acc[0][3]);
            acc[1][0] = fmaf(a1, wv.x, acc[1][0]);
            acc[1][1] = fmaf(a1, wv.y, acc[1][1]);
            acc[1][2] = fmaf(a1, wv.z, acc[1][2]);
            acc[1][3] = fmaf(a1, wv.w, acc[1][3]);
            acc[2][0] = fmaf(a2, wv.x, acc[2][0]);
            acc[2][1] = fmaf(a2, wv.y, acc[2][1]);
            acc[2][2] = fmaf(a2, wv.z, acc[2][2]);
            acc[2][3] = fmaf(a2, wv.w, acc[2][3]);
            acc[3][0] = fmaf(a3, wv.x, acc[3][0]);
            acc[3][1] = fmaf(a3, wv.y, acc[3][1]);
            acc[3][2] = fmaf(a3, wv.z, acc[3][2]);
            acc[3][3] = fmaf(a3, wv.w, acc[3][3]);
        }
    }
    #pragma unroll
    for (int i = 0; i < 4; ++i) {
        float4 o = make_float4(acc[i][0], acc[i][1], acc[i][2], acc[i][3]);
        *(float4*)&C[(size_t)(rowBase + 4 * tr + i) * NFEAT + 4 * tc] = o;
    }
}

// ---------------- aggregation: H[n] = relu( dinv[n]^2*XW[n] + sum_e w*XW[col] + b ) ----------------
// one wave per node, float2 per lane (128 cols)
__global__ __launch_bounds__(256) void k_agg(const float* __restrict__ XW, const int* __restrict__ col,
                                             const float* __restrict__ wgt, const int* __restrict__ off,
                                             const float* __restrict__ dinv, const float* __restrict__ bias,
                                             float* __restrict__ H) {
    int wid = (blockIdx.x * blockDim.x + threadIdx.x) >> 6;
    int lane = threadIdx.x & 63;
    if (wid >= N_NODES) return;
    int n = wid;
    float dn = dinv[n];
    float2 v = ((const float2*)(XW + (size_t)n * NFEAT))[lane];
    float2 acc;
    acc.x = dn * dn * v.x;
    acc.y = dn * dn * v.y;
    int e0 = off[n], e1 = off[n + 1];
    for (int e = e0; e < e1; ++e) {
        int c = col[e];
        float w = wgt[e];
        float2 u = ((const float2*)(XW + (size_t)c * NFEAT))[lane];
        acc.x = fmaf(w, u.x, acc.x);
        acc.y = fmaf(w, u.y, acc.y);
    }
    float2 bb = ((const float2*)bias)[lane];
    acc.x = fmaxf(acc.x + bb.x, 0.f);
    acc.y = fmaxf(acc.y + bb.y, 0.f);
    ((float2*)(H + (size_t)n * NFEAT))[lane] = acc;
}

// ---------------- fused mean-pool + FC: per-node dot with Wfc, segment-sum by graph ----------------
__global__ __launch_bounds__(256) void k_pool(const float* __restrict__ H, const int* __restrict__ batch,
                                              const float* __restrict__ Wfc, float* gsum, float* gcnt) {
    int wid = (blockIdx.x * blockDim.x + threadIdx.x) >> 6;
    int lane = threadIdx.x & 63;
    if (wid >= N_NODES) return;
    float2 h = ((const float2*)(H + (size_t)wid * NFEAT))[lane];
    float2 w = ((const float2*)Wfc)[lane];
    float s = h.x * w.x + h.y * w.y;
    for (int d = 32; d > 0; d >>= 1) s += __shfl_down(s, d, 64);
    if (lane == 0) {
        int g = batch[wid];
        atomicAdd(&gsum[g], s);
        atomicAdd(&gcnt[g], 1.0f);
    }
}

__global__ __launch_bounds__(256) void k_final(const float* __restrict__ gsum,
                                               const float* __restrict__ gcnt,
                                               const float* __restrict__ bfc, float* out) {
    int g = blockIdx.x * blockDim.x + threadIdx.x;
    if (g < N_GRAPHS) out[g] = gsum[g] / fmaxf(gcnt[g], 1.0f) + bfc[0];
}

// ---------------- launch ----------------
extern "C" void kernel_launch(void* const* d_in, const int* in_sizes, int n_in,
                              void* d_out, int out_size, void* d_ws, size_t ws_size,
                              hipStream_t stream) {
    const float* x    = (const float*)d_in[0];
    const int*   ei   = (const int*)d_in[1];     // [2, E] : row0 = src, row1 = dst
    const int*   batch= (const int*)d_in[2];
    const float* W1   = (const float*)d_in[3];
    const float* b1   = (const float*)d_in[4];
    const float* W2   = (const float*)d_in[5];
    const float* b2   = (const float*)d_in[6];
    const float* W3   = (const float*)d_in[7];
    const float* b3   = (const float*)d_in[8];
    const float* Wfc  = (const float*)d_in[9];
    const float* bfc  = (const float*)d_in[10];
    float* out = (float*)d_out;

    const int* src = ei;
    const int* dst = ei + N_EDGES;

    // carve workspace (256B-aligned)
    char* p = (char*)d_ws;
    auto carve = [&](size_t bytes) { void* r = (void*)p; p += (bytes + 255) & ~(size_t)255; return r; };
    int*   counts    = (int*)  carve(sizeof(int)   * N_NODES);
    float* dinv      = (float*)carve(sizeof(float) * N_NODES);
    int*   offsets   = (int*)  carve(sizeof(int)   * (N_NODES + 1));
    int*   cursor    = (int*)  carve(sizeof(int)   * N_NODES);
    int*   col       = (int*)  carve(sizeof(int)   * N_EDGES);
    float* wgt       = (float*)carve(sizeof(float) * N_EDGES);
    float* XW        = (float*)carve(sizeof(float) * (size_t)N_NODES * NFEAT);
    float* H         = (float*)carve(sizeof(float) * (size_t)N_NODES * NFEAT);
    float* gsum      = (float*)carve(sizeof(float) * N_GRAPHS);
    float* gcnt      = (float*)carve(sizeof(float) * N_GRAPHS);
    int*   blockSums = (int*)  carve(sizeof(int)   * SCAN_BLOCKS);
    int*   blockOffs = (int*)  carve(sizeof(int)   * SCAN_BLOCKS);

    const int nodeBlocks = (N_NODES + 255) / 256;            // 391
    const int edgeBlocks = (N_EDGES + 255) / 256;            // 6250
    const int waveNodeBlocks = (N_NODES * 64 + 255) / 256;   // 25000

    k_init<<<nodeBlocks, 256, 0, stream>>>(counts, gsum, gcnt);
    k_hist<<<edgeBlocks, 256, 0, stream>>>(dst, counts);
    k_dinv<<<nodeBlocks, 256, 0, stream>>>(counts, dinv);
    k_scan_partial<<<SCAN_BLOCKS, 256, 0, stream>>>(counts, blockSums);
    k_scan_blocksums<<<1, 1, 0, stream>>>(blockSums, blockOffs, offsets);
    k_scan_final<<<SCAN_BLOCKS, 256, 0, stream>>>(counts, blockOffs, offsets, cursor);
    k_fill<<<edgeBlocks, 256, 0, stream>>>(src, dst, dinv, cursor, col, wgt);

    // layer 1
    k_gemm<<<N_NODES / GM, 256, 0, stream>>>(x, W1, XW);
    k_agg<<<waveNodeBlocks, 256, 0, stream>>>(XW, col, wgt, offsets, dinv, b1, H);
    // layer 2
    k_gemm<<<N_NODES / GM, 256, 0, stream>>>(H, W2, XW);
    k_agg<<<waveNodeBlocks, 256, 0, stream>>>(XW, col, wgt, offsets, dinv, b2, H);
    // layer 3
    k_gemm<<<N_NODES / GM, 256, 0, stream>>>(H, W3, XW);
    k_agg<<<waveNodeBlocks, 256, 0, stream>>>(XW, col, wgt, offsets, dinv, b3, H);

    // pooled mean + FC
    k_pool<<<waveNodeBlocks, 256, 0, stream>>>(H, batch, Wfc, gsum, gcnt);
    k_final<<<(N_GRAPHS + 255) / 256, 256, 0, stream>>>(gsum, gcnt, bfc, out);
}

// Round 2
// 976.762 us; speedup vs baseline: 1.1162x; 1.1162x over previous
//
#include <hip/hip_runtime.h>

#define N_NODES   100000
#define N_EDGES   1600000
#define NFEAT     128
#define N_GRAPHS  1024

#define SCAN_CHUNK  1024
#define SCAN_BLOCKS ((N_NODES + SCAN_CHUNK - 1) / SCAN_CHUNK)   // 98

// ---------------- init: zero counts + pool accumulators ----------------
__global__ __launch_bounds__(256) void k_init(int* counts, float* gsum, float* gcnt) {
    int i = blockIdx.x * blockDim.x + threadIdx.x;
    if (i < N_NODES) counts[i] = 0;
    if (i < N_GRAPHS) { gsum[i] = 0.f; gcnt[i] = 0.f; }
}

// ---------------- in-degree histogram over dst ----------------
__global__ __launch_bounds__(256) void k_hist(const int* __restrict__ dst, int* counts) {
    int e = blockIdx.x * blockDim.x + threadIdx.x;
    if (e < N_EDGES) atomicAdd(&counts[dst[e]], 1);
}

// ---------------- deg^{-1/2} + per-graph node counts ----------------
__global__ __launch_bounds__(256) void k_dinv(const int* __restrict__ counts, float* dinv,
                                              const int* __restrict__ batch, float* gcnt) {
    int n = blockIdx.x * blockDim.x + threadIdx.x;
    if (n < N_NODES) {
        dinv[n] = rsqrtf((float)(counts[n] + 1));
        atomicAdd(&gcnt[batch[n]], 1.0f);
    }
}

// ---------------- exclusive scan of counts -> offsets (3 phases) ----------------
__global__ __launch_bounds__(256) void k_scan_partial(const int* __restrict__ counts, int* blockSums) {
    int base = blockIdx.x * SCAN_CHUNK;
    int t = threadIdx.x;
    int s = 0;
    for (int i = t; i < SCAN_CHUNK; i += 256) {
        int idx = base + i;
        if (idx < N_NODES) s += counts[idx];
    }
    for (int d = 32; d > 0; d >>= 1) s += __shfl_down(s, d, 64);
    __shared__ int lds[4];
    int lane = t & 63, w = t >> 6;
    if (lane == 0) lds[w] = s;
    __syncthreads();
    if (t == 0) blockSums[blockIdx.x] = lds[0] + lds[1] + lds[2] + lds[3];
}

__global__ void k_scan_blocksums(int* blockSums, int* blockOffs, int* offsets) {
    int run = 0;
    for (int b = 0; b < SCAN_BLOCKS; ++b) { blockOffs[b] = run; run += blockSums[b]; }
    offsets[N_NODES] = run;   // == N_EDGES
}

__global__ __launch_bounds__(256) void k_scan_final(const int* __restrict__ counts,
                                                    const int* __restrict__ blockOffs,
                                                    int* offsets, int* cursor) {
    int base = blockIdx.x * SCAN_CHUNK;
    int t = threadIdx.x;
    int c[4];
    int ts = 0;
    #pragma unroll
    for (int i = 0; i < 4; ++i) {
        int idx = base + 4 * t + i;
        c[i] = (idx < N_NODES) ? counts[idx] : 0;
        ts += c[i];
    }
    int lane = t & 63, w = t >> 6;
    int inc = ts;
    #pragma unroll
    for (int d = 1; d < 64; d <<= 1) {
        int v = __shfl_up(inc, d, 64);
        if (lane >= d) inc += v;
    }
    __shared__ int wsum[4];
    if (lane == 63) wsum[w] = inc;
    __syncthreads();
    int wpre = 0;
    for (int i = 0; i < w; ++i) wpre += wsum[i];
    int run = blockOffs[blockIdx.x] + wpre + (inc - ts);
    #pragma unroll
    for (int i = 0; i < 4; ++i) {
        int idx = base + 4 * t + i;
        if (idx < N_NODES) { offsets[idx] = run; cursor[idx] = run; }
        run += c[i];
    }
}

// ---------------- CSR fill: col (src idx) + edge weight ----------------
__global__ __launch_bounds__(256) void k_fill(const int* __restrict__ src, const int* __restrict__ dst,
                                              const float* __restrict__ dinv, int* cursor,
                                              int* col, float* wgt) {
    int e = blockIdx.x * blockDim.x + threadIdx.x;
    if (e < N_EDGES) {
        int s = src[e], d = dst[e];
        int p = atomicAdd(&cursor[d], 1);
        col[p] = s;
        wgt[p] = dinv[s] * dinv[d];
    }
}

// ---------------- fp32 GEMM: C[M,128] = A[M,128] @ W[128,128] ----------------
// Full W in LDS (64KB, staged once). 128-row block tile, A staged transposed
// per 32-k tile so inner loop is 4x ds_read_b128 + 64 FMA per k.
// LDS = 80KB -> 2 blocks/CU; VGPR ~100 -> fine at 2 waves/EU.
#define TM  128
#define TKB 32
__global__ __launch_bounds__(256, 2) void k_gemm(const float* __restrict__ A,
                                                 const float* __restrict__ W,
                                                 float* __restrict__ C, int M) {
    __shared__ float sW[128 * 128];     // [k][n]  64 KB, resident whole kernel
    __shared__ float sAT[TKB * 128];    // [k][m]  16 KB, per k-tile
    int t = threadIdx.x;
    int tc = t & 15;         // col block: cols 8*tc .. 8*tc+7
    int tr = t >> 4;         // row block: rows 8*tr .. 8*tr+7
    int rowBase = blockIdx.x * TM;

    // stage W once (each thread 16 float4)
    {
        const float4* W4 = (const float4*)W;
        float4* sW4 = (float4*)sW;
        #pragma unroll
        for (int i = 0; i < 16; ++i) sW4[t + 256 * i] = W4[t + 256 * i];
    }

    float acc[8][8];
    #pragma unroll
    for (int i = 0; i < 8; ++i)
        #pragma unroll
        for (int j = 0; j < 8; ++j) acc[i][j] = 0.f;

    int rr = t >> 1;          // staging row within tile (0..127)
    int half = t & 1;         // staging k-half (0 or 1 -> k offset 0/16)
    int gr = rowBase + rr;
    bool ok = gr < M;
    const float* Arow = A + (size_t)(ok ? gr : 0) * NFEAT;

    for (int kt = 0; kt < NFEAT; kt += TKB) {
        __syncthreads();
        // stage A[rr][kt+16*half .. +16) -> sAT[k][rr]
        {
            float4 v0, v1, v2, v3;
            if (ok) {
                const float4* Ap = (const float4*)(Arow + kt + 16 * half);
                v0 = Ap[0]; v1 = Ap[1]; v2 = Ap[2]; v3 = Ap[3];
            } else {
                v0 = v1 = v2 = v3 = make_float4(0.f, 0.f, 0.f, 0.f);
            }
            int kb = 16 * half;
            sAT[(kb + 0) * 128 + rr] = v0.x;  sAT[(kb + 1) * 128 + rr] = v0.y;
            sAT[(kb + 2) * 128 + rr] = v0.z;  sAT[(kb + 3) * 128 + rr] = v0.w;
            sAT[(kb + 4) * 128 + rr] = v1.x;  sAT[(kb + 5) * 128 + rr] = v1.y;
            sAT[(kb + 6) * 128 + rr] = v1.z;  sAT[(kb + 7) * 128 + rr] = v1.w;
            sAT[(kb + 8) * 128 + rr] = v2.x;  sAT[(kb + 9) * 128 + rr] = v2.y;
            sAT[(kb + 10) * 128 + rr] = v2.z; sAT[(kb + 11) * 128 + rr] = v2.w;
            sAT[(kb + 12) * 128 + rr] = v3.x; sAT[(kb + 13) * 128 + rr] = v3.y;
            sAT[(kb + 14) * 128 + rr] = v3.z; sAT[(kb + 15) * 128 + rr] = v3.w;
        }
        __syncthreads();
        #pragma unroll
        for (int k = 0; k < TKB; ++k) {
            float4 a0 = *(const float4*)&sAT[k * 128 + 8 * tr];
            float4 a1 = *(const float4*)&sAT[k * 128 + 8 * tr + 4];
            float4 w0 = *(const float4*)&sW[(kt + k) * 128 + 8 * tc];
            float4 w1 = *(const float4*)&sW[(kt + k) * 128 + 8 * tc + 4];
            float av[8] = {a0.x, a0.y, a0.z, a0.w, a1.x, a1.y, a1.z, a1.w};
            float wv[8] = {w0.x, w0.y, w0.z, w0.w, w1.x, w1.y, w1.z, w1.w};
            #pragma unroll
            for (int i = 0; i < 8; ++i)
                #pragma unroll
                for (int j = 0; j < 8; ++j)
                    acc[i][j] = fmaf(av[i], wv[j], acc[i][j]);
        }
    }

    #pragma unroll
    for (int i = 0; i < 8; ++i) {
        int grow = rowBase + 8 * tr + i;
        if (grow < M) {
            float* Cp = C + (size_t)grow * NFEAT + 8 * tc;
            *(float4*)Cp       = make_float4(acc[i][0], acc[i][1], acc[i][2], acc[i][3]);
            *(float4*)(Cp + 4) = make_float4(acc[i][4], acc[i][5], acc[i][6], acc[i][7]);
        }
    }
}

// ---------------- aggregation: H[n] = relu( dinv[n]^2*XW[n] + sum_e w*XW[col] + b ) ----------------
// one wave per node, float2 per lane; edge loop unrolled x4 for MLP
__global__ __launch_bounds__(256) void k_agg(const float* __restrict__ XW, const int* __restrict__ col,
                                             const float* __restrict__ wgt, const int* __restrict__ off,
                                             const float* __restrict__ dinv, const float* __restrict__ bias,
                                             float* __restrict__ H) {
    int wid = (blockIdx.x * blockDim.x + threadIdx.x) >> 6;
    int lane = threadIdx.x & 63;
    if (wid >= N_NODES) return;
    int n = wid;
    float dn = dinv[n];
    const float2* XW2 = (const float2*)XW;
    float2 v = XW2[(size_t)n * 64 + lane];
    float ax = dn * dn * v.x;
    float ay = dn * dn * v.y;
    int e0 = off[n], e1 = off[n + 1];
    int e = e0;
    for (; e + 4 <= e1; e += 4) {
        int c0 = col[e], c1 = col[e + 1], c2 = col[e + 2], c3 = col[e + 3];
        float w0 = wgt[e], w1 = wgt[e + 1], w2 = wgt[e + 2], w3 = wgt[e + 3];
        float2 u0 = XW2[(size_t)c0 * 64 + lane];
        float2 u1 = XW2[(size_t)c1 * 64 + lane];
        float2 u2 = XW2[(size_t)c2 * 64 + lane];
        float2 u3 = XW2[(size_t)c3 * 64 + lane];
        ax = fmaf(w0, u0.x, ax); ay = fmaf(w0, u0.y, ay);
        ax = fmaf(w1, u1.x, ax); ay = fmaf(w1, u1.y, ay);
        ax = fmaf(w2, u2.x, ax); ay = fmaf(w2, u2.y, ay);
        ax = fmaf(w3, u3.x, ax); ay = fmaf(w3, u3.y, ay);
    }
    for (; e < e1; ++e) {
        int c = col[e];
        float w = wgt[e];
        float2 u = XW2[(size_t)c * 64 + lane];
        ax = fmaf(w, u.x, ax); ay = fmaf(w, u.y, ay);
    }
    float2 bb = ((const float2*)bias)[lane];
    float2 o;
    o.x = fmaxf(ax + bb.x, 0.f);
    o.y = fmaxf(ay + bb.y, 0.f);
    ((float2*)H)[(size_t)n * 64 + lane] = o;
}

// ---------------- fused layer-3 aggregation + relu + FC-dot + graph segment-sum ----------------
__global__ __launch_bounds__(256) void k_agg_pool(const float* __restrict__ XW, const int* __restrict__ col,
                                                  const float* __restrict__ wgt, const int* __restrict__ off,
                                                  const float* __restrict__ dinv, const float* __restrict__ bias,
                                                  const int* __restrict__ batch, const float* __restrict__ Wfc,
                                                  float* gsum) {
    int wid = (blockIdx.x * blockDim.x + threadIdx.x) >> 6;
    int lane = threadIdx.x & 63;
    if (wid >= N_NODES) return;
    int n = wid;
    float dn = dinv[n];
    const float2* XW2 = (const float2*)XW;
    float2 v = XW2[(size_t)n * 64 + lane];
    float ax = dn * dn * v.x;
    float ay = dn * dn * v.y;
    int e0 = off[n], e1 = off[n + 1];
    int e = e0;
    for (; e + 4 <= e1; e += 4) {
        int c0 = col[e], c1 = col[e + 1], c2 = col[e + 2], c3 = col[e + 3];
        float w0 = wgt[e], w1 = wgt[e + 1], w2 = wgt[e + 2], w3 = wgt[e + 3];
        float2 u0 = XW2[(size_t)c0 * 64 + lane];
        float2 u1 = XW2[(size_t)c1 * 64 + lane];
        float2 u2 = XW2[(size_t)c2 * 64 + lane];
        float2 u3 = XW2[(size_t)c3 * 64 + lane];
        ax = fmaf(w0, u0.x, ax); ay = fmaf(w0, u0.y, ay);
        ax = fmaf(w1, u1.x, ax); ay = fmaf(w1, u1.y, ay);
        ax = fmaf(w2, u2.x, ax); ay = fmaf(w2, u2.y, ay);
        ax = fmaf(w3, u3.x, ax); ay = fmaf(w3, u3.y, ay);
    }
    for (; e < e1; ++e) {
        int c = col[e];
        float w = wgt[e];
        float2 u = XW2[(size_t)c * 64 + lane];
        ax = fmaf(w, u.x, ax); ay = fmaf(w, u.y, ay);
    }
    float2 bb = ((const float2*)bias)[lane];
    float hx = fmaxf(ax + bb.x, 0.f);
    float hy = fmaxf(ay + bb.y, 0.f);
    float2 wf = ((const float2*)Wfc)[lane];
    float s = hx * wf.x + hy * wf.y;
    for (int d = 32; d > 0; d >>= 1) s += __shfl_down(s, d, 64);
    if (lane == 0) atomicAdd(&gsum[batch[n]], s);
}

__global__ __launch_bounds__(256) void k_final(const float* __restrict__ gsum,
                                               const float* __restrict__ gcnt,
                                               const float* __restrict__ bfc, float* out) {
    int g = blockIdx.x * blockDim.x + threadIdx.x;
    if (g < N_GRAPHS) out[g] = gsum[g] / fmaxf(gcnt[g], 1.0f) + bfc[0];
}

// ---------------- launch ----------------
extern "C" void kernel_launch(void* const* d_in, const int* in_sizes, int n_in,
                              void* d_out, int out_size, void* d_ws, size_t ws_size,
                              hipStream_t stream) {
    const float* x    = (const float*)d_in[0];
    const int*   ei   = (const int*)d_in[1];     // [2, E] : row0 = src, row1 = dst
    const int*   batch= (const int*)d_in[2];
    const float* W1   = (const float*)d_in[3];
    const float* b1   = (const float*)d_in[4];
    const float* W2   = (const float*)d_in[5];
    const float* b2   = (const float*)d_in[6];
    const float* W3   = (const float*)d_in[7];
    const float* b3   = (const float*)d_in[8];
    const float* Wfc  = (const float*)d_in[9];
    const float* bfc  = (const float*)d_in[10];
    float* out = (float*)d_out;

    const int* src = ei;
    const int* dst = ei + N_EDGES;

    // carve workspace (256B-aligned)
    char* p = (char*)d_ws;
    auto carve = [&](size_t bytes) { void* r = (void*)p; p += (bytes + 255) & ~(size_t)255; return r; };
    int*   counts    = (int*)  carve(sizeof(int)   * N_NODES);
    float* dinv      = (float*)carve(sizeof(float) * N_NODES);
    int*   offsets   = (int*)  carve(sizeof(int)   * (N_NODES + 1));
    int*   cursor    = (int*)  carve(sizeof(int)   * N_NODES);
    int*   col       = (int*)  carve(sizeof(int)   * N_EDGES);
    float* wgt       = (float*)carve(sizeof(float) * N_EDGES);
    float* XW        = (float*)carve(sizeof(float) * (size_t)N_NODES * NFEAT);
    float* H         = (float*)carve(sizeof(float) * (size_t)N_NODES * NFEAT);
    float* gsum      = (float*)carve(sizeof(float) * N_GRAPHS);
    float* gcnt      = (float*)carve(sizeof(float) * N_GRAPHS);
    int*   blockSums = (int*)  carve(sizeof(int)   * SCAN_BLOCKS);
    int*   blockOffs = (int*)  carve(sizeof(int)   * SCAN_BLOCKS);

    const int nodeBlocks = (N_NODES + 255) / 256;            // 391
    const int edgeBlocks = (N_EDGES + 255) / 256;            // 6250
    const int waveNodeBlocks = (N_NODES * 64 + 255) / 256;   // 25000
    const int gemmBlocks = (N_NODES + TM - 1) / TM;          // 782

    k_init<<<nodeBlocks, 256, 0, stream>>>(counts, gsum, gcnt);
    k_hist<<<edgeBlocks, 256, 0, stream>>>(dst, counts);
    k_dinv<<<nodeBlocks, 256, 0, stream>>>(counts, dinv, batch, gcnt);
    k_scan_partial<<<SCAN_BLOCKS, 256, 0, stream>>>(counts, blockSums);
    k_scan_blocksums<<<1, 1, 0, stream>>>(blockSums, blockOffs, offsets);
    k_scan_final<<<SCAN_BLOCKS, 256, 0, stream>>>(counts, blockOffs, offsets, cursor);
    k_fill<<<edgeBlocks, 256, 0, stream>>>(src, dst, dinv, cursor, col, wgt);

    // layer 1
    k_gemm<<<gemmBlocks, 256, 0, stream>>>(x, W1, XW, N_NODES);
    k_agg<<<waveNodeBlocks, 256, 0, stream>>>(XW, col, wgt, offsets, dinv, b1, H);
    // layer 2
    k_gemm<<<gemmBlocks, 256, 0, stream>>>(H, W2, XW, N_NODES);
    k_agg<<<waveNodeBlocks, 256, 0, stream>>>(XW, col, wgt, offsets, dinv, b2, H);
    // layer 3
    k_gemm<<<gemmBlocks, 256, 0, stream>>>(H, W3, XW, N_NODES);
    k_agg_pool<<<waveNodeBlocks, 256, 0, stream>>>(XW, col, wgt, offsets, dinv, b3, batch, Wfc, gsum);

    k_final<<<(N_GRAPHS + 255) / 256, 256, 0, stream>>>(gsum, gcnt, bfc, out);
}

// Round 3
// 588.605 us; speedup vs baseline: 1.8523x; 1.6595x over previous
//
#include <hip/hip_runtime.h>

#define N_NODES   100000
#define N_EDGES   1600000
#define NFEAT     128
#define N_GRAPHS  1024

#define SCAN_CHUNK  1024
#define SCAN_BLOCKS ((N_NODES + SCAN_CHUNK - 1) / SCAN_CHUNK)   // 98

typedef unsigned int uint32;
typedef unsigned short ushort16;
typedef __attribute__((ext_vector_type(8))) short short8;   // 8 bf16 (4 VGPRs)
typedef __attribute__((ext_vector_type(4))) float f32x4;

// fp32 -> bf16 bits, round-to-nearest-even (finite inputs)
__device__ inline unsigned short f2b(float f) {
    uint32 x = __float_as_uint(f);
    uint32 r = x + 0x7fffu + ((x >> 16) & 1u);
    return (unsigned short)(r >> 16);
}
__device__ inline float blo(uint32 u) { return __uint_as_float(u << 16); }
__device__ inline float bhi(uint32 u) { return __uint_as_float(u & 0xffff0000u); }

// ---------------- init: zero degree counts ----------------
__global__ __launch_bounds__(256) void k_init(int* counts) {
    int i = blockIdx.x * blockDim.x + threadIdx.x;
    if (i < N_NODES) counts[i] = 0;
}

// ---------------- in-degree histogram over dst ----------------
__global__ __launch_bounds__(256) void k_hist(const int* __restrict__ dst, int* counts) {
    int e = blockIdx.x * blockDim.x + threadIdx.x;
    if (e < N_EDGES) atomicAdd(&counts[dst[e]], 1);
}

// ---------------- deg^{-1/2} (self-loop makes deg >= 1) ----------------
__global__ __launch_bounds__(256) void k_dinv(const int* __restrict__ counts, float* dinv) {
    int n = blockIdx.x * blockDim.x + threadIdx.x;
    if (n < N_NODES) dinv[n] = rsqrtf((float)(counts[n] + 1));
}

// ---------------- exclusive scan of counts -> offsets ----------------
__global__ __launch_bounds__(256) void k_scan_partial(const int* __restrict__ counts, int* blockSums) {
    int base = blockIdx.x * SCAN_CHUNK;
    int t = threadIdx.x;
    int s = 0;
    for (int i = t; i < SCAN_CHUNK; i += 256) {
        int idx = base + i;
        if (idx < N_NODES) s += counts[idx];
    }
    for (int d = 32; d > 0; d >>= 1) s += __shfl_down(s, d, 64);
    __shared__ int lds[4];
    int lane = t & 63, w = t >> 6;
    if (lane == 0) lds[w] = s;
    __syncthreads();
    if (t == 0) blockSums[blockIdx.x] = lds[0] + lds[1] + lds[2] + lds[3];
}

__global__ void k_scan_blocksums(int* blockSums, int* blockOffs, int* offsets) {
    int run = 0;
    for (int b = 0; b < SCAN_BLOCKS; ++b) { blockOffs[b] = run; run += blockSums[b]; }
    offsets[N_NODES] = run;   // == N_EDGES
}

__global__ __launch_bounds__(256) void k_scan_final(const int* __restrict__ counts,
                                                    const int* __restrict__ blockOffs,
                                                    int* offsets, int* cursor) {
    int base = blockIdx.x * SCAN_CHUNK;
    int t = threadIdx.x;
    int c[4];
    int ts = 0;
    #pragma unroll
    for (int i = 0; i < 4; ++i) {
        int idx = base + 4 * t + i;
        c[i] = (idx < N_NODES) ? counts[idx] : 0;
        ts += c[i];
    }
    int lane = t & 63, w = t >> 6;
    int inc = ts;
    #pragma unroll
    for (int d = 1; d < 64; d <<= 1) {
        int v = __shfl_up(inc, d, 64);
        if (lane >= d) inc += v;
    }
    __shared__ int wsum[4];
    if (lane == 63) wsum[w] = inc;
    __syncthreads();
    int wpre = 0;
    for (int i = 0; i < w; ++i) wpre += wsum[i];
    int run = blockOffs[blockIdx.x] + wpre + (inc - ts);
    #pragma unroll
    for (int i = 0; i < 4; ++i) {
        int idx = base + 4 * t + i;
        if (idx < N_NODES) { offsets[idx] = run; cursor[idx] = run; }
        run += c[i];
    }
}

// ---------------- CSR fill ----------------
__global__ __launch_bounds__(256) void k_fill(const int* __restrict__ src, const int* __restrict__ dst,
                                              const float* __restrict__ dinv, int* cursor,
                                              int* col, float* wgt) {
    int e = blockIdx.x * blockDim.x + threadIdx.x;
    if (e < N_EDGES) {
        int s = src[e], d = dst[e];
        int p = atomicAdd(&cursor[d], 1);
        col[p] = s;
        wgt[p] = dinv[s] * dinv[d];
    }
}

// ---------------- cast x (fp32) -> bf16 ----------------
__global__ __launch_bounds__(256) void k_cast(const float* __restrict__ x, unsigned short* __restrict__ xb) {
    const int total4 = N_NODES * NFEAT / 4;   // 3.2M float4s
    for (int i = blockIdx.x * blockDim.x + threadIdx.x; i < total4; i += gridDim.x * blockDim.x) {
        float4 v = ((const float4*)x)[i];
        uint32 lo = (uint32)f2b(v.x) | ((uint32)f2b(v.y) << 16);
        uint32 hi = (uint32)f2b(v.z) | ((uint32)f2b(v.w) << 16);
        ((uint2*)xb)[i] = make_uint2(lo, hi);
    }
}

// ---------------- cast + transpose W1,W2,W3 -> WT bf16 [layer][n][k] ----------------
__global__ __launch_bounds__(256) void k_castw(const float* __restrict__ W1, const float* __restrict__ W2,
                                               const float* __restrict__ W3, unsigned short* __restrict__ WT) {
    int i = blockIdx.x * blockDim.x + threadIdx.x;   // 3*16384
    if (i >= 3 * NFEAT * NFEAT) return;
    int l = i >> 14;
    int j = i & 16383;
    int n = j >> 7;
    int k = j & 127;
    const float* W = (l == 0) ? W1 : (l == 1) ? W2 : W3;
    WT[i] = f2b(W[k * NFEAT + n]);   // WT[l][n*128+k] = W[k][n]
}

// ---------------- bf16 MFMA GEMM: C[M,128] = A[M,128] @ W ----------------
// A bf16 row-major, WT bf16 [n][k] (transposed), C bf16 row-major.
// Block = 256 thr = 4 waves, 64 rows/block; wave computes 16 rows x 128 cols.
// A-frags loaded straight from global (lane l: row m0+(l&15), k = (l>>4)*8 + j).
// W^T staged in LDS, row stride 136 (+8 pad -> only 2-way bank aliasing, free).
#define WT_STRIDE 136
__global__ __launch_bounds__(256) void k_gemm(const unsigned short* __restrict__ A,
                                              const unsigned short* __restrict__ WTl,
                                              unsigned short* __restrict__ C, int M) {
    __shared__ unsigned short sWT[NFEAT * WT_STRIDE];   // 34 KB
    int t = threadIdx.x;
    // stage W^T (row n: 128 bf16 = 16 chunks of 16B)
    for (int i = t; i < NFEAT * 16; i += 256) {
        int n = i >> 4, c = i & 15;
        *(float4*)(sWT + n * WT_STRIDE + c * 8) = ((const float4*)WTl)[i];
    }
    int wave = t >> 6, lane = t & 63;
    int m0 = blockIdx.x * 64 + wave * 16;
    int mRow = m0 + (lane & 15);
    if (mRow >= M) mRow = M - 1;            // clamp loads; stores predicated
    int kg = lane >> 4;                      // k-group 0..3
    const short8* Ap = (const short8*)(A + (size_t)mRow * NFEAT + kg * 8);
    short8 a0 = Ap[0];     // k in [kg*8, kg*8+8)
    short8 a1 = Ap[4];     // +32
    short8 a2 = Ap[8];     // +64
    short8 a3 = Ap[12];    // +96
    __syncthreads();

    f32x4 acc[8];
    #pragma unroll
    for (int nt = 0; nt < 8; ++nt) acc[nt] = (f32x4){0.f, 0.f, 0.f, 0.f};

    #pragma unroll
    for (int nt = 0; nt < 8; ++nt) {
        int n = nt * 16 + (lane & 15);
        const short8* Bp = (const short8*)(sWT + n * WT_STRIDE + kg * 8);
        short8 b0 = Bp[0];
        short8 b1 = Bp[4];
        short8 b2 = Bp[8];
        short8 b3 = Bp[12];
        acc[nt] = __builtin_amdgcn_mfma_f32_16x16x32_bf16(a0, b0, acc[nt], 0, 0, 0);
        acc[nt] = __builtin_amdgcn_mfma_f32_16x16x32_bf16(a1, b1, acc[nt], 0, 0, 0);
        acc[nt] = __builtin_amdgcn_mfma_f32_16x16x32_bf16(a2, b2, acc[nt], 0, 0, 0);
        acc[nt] = __builtin_amdgcn_mfma_f32_16x16x32_bf16(a3, b3, acc[nt], 0, 0, 0);
    }

    // D layout: col = lane&15, row = kg*4 + r   [m89-verified]
    int colBase = lane & 15;
    #pragma unroll
    for (int r = 0; r < 4; ++r) {
        int gr = m0 + kg * 4 + r;
        if (gr < M) {
            unsigned short* Cp = C + (size_t)gr * NFEAT + colBase;
            #pragma unroll
            for (int nt = 0; nt < 8; ++nt) Cp[nt * 16] = f2b(acc[nt][r]);
        }
    }
}

// ---------------- aggregation (bf16 rows): H[n] = relu(dinv^2*XW[n] + sum w*XW[col] + b) ----------------
__global__ __launch_bounds__(256) void k_agg(const uint32* __restrict__ XWu, const int* __restrict__ col,
                                             const float* __restrict__ wgt, const int* __restrict__ off,
                                             const float* __restrict__ dinv, const float* __restrict__ bias,
                                             uint32* __restrict__ Hu) {
    int wid = (blockIdx.x * blockDim.x + threadIdx.x) >> 6;
    int lane = threadIdx.x & 63;
    if (wid >= N_NODES) return;
    int n = wid;
    float dn = dinv[n];
    uint32 v = XWu[(size_t)n * 64 + lane];
    float ax = dn * dn * blo(v);
    float ay = dn * dn * bhi(v);
    int e0 = off[n], e1 = off[n + 1];
    int e = e0;
    for (; e + 4 <= e1; e += 4) {
        int c0 = col[e], c1 = col[e + 1], c2 = col[e + 2], c3 = col[e + 3];
        float w0 = wgt[e], w1 = wgt[e + 1], w2 = wgt[e + 2], w3 = wgt[e + 3];
        uint32 u0 = XWu[(size_t)c0 * 64 + lane];
        uint32 u1 = XWu[(size_t)c1 * 64 + lane];
        uint32 u2 = XWu[(size_t)c2 * 64 + lane];
        uint32 u3 = XWu[(size_t)c3 * 64 + lane];
        ax = fmaf(w0, blo(u0), ax); ay = fmaf(w0, bhi(u0), ay);
        ax = fmaf(w1, blo(u1), ax); ay = fmaf(w1, bhi(u1), ay);
        ax = fmaf(w2, blo(u2), ax); ay = fmaf(w2, bhi(u2), ay);
        ax = fmaf(w3, blo(u3), ax); ay = fmaf(w3, bhi(u3), ay);
    }
    for (; e < e1; ++e) {
        int c = col[e];
        float w = wgt[e];
        uint32 u = XWu[(size_t)c * 64 + lane];
        ax = fmaf(w, blo(u), ax); ay = fmaf(w, bhi(u), ay);
    }
    float2 bb = ((const float2*)bias)[lane];
    float ox = fmaxf(ax + bb.x, 0.f);
    float oy = fmaxf(ay + bb.y, 0.f);
    Hu[(size_t)n * 64 + lane] = (uint32)f2b(ox) | ((uint32)f2b(oy) << 16);
}

// ---------------- layer-3 aggregation + relu + FC dot -> per-node scalar (no atomics) ----------------
__global__ __launch_bounds__(256) void k_agg_fc(const uint32* __restrict__ XWu, const int* __restrict__ col,
                                                const float* __restrict__ wgt, const int* __restrict__ off,
                                                const float* __restrict__ dinv, const float* __restrict__ bias,
                                                const float* __restrict__ Wfc, float* __restrict__ nodeS) {
    int wid = (blockIdx.x * blockDim.x + threadIdx.x) >> 6;
    int lane = threadIdx.x & 63;
    if (wid >= N_NODES) return;
    int n = wid;
    float dn = dinv[n];
    uint32 v = XWu[(size_t)n * 64 + lane];
    float ax = dn * dn * blo(v);
    float ay = dn * dn * bhi(v);
    int e0 = off[n], e1 = off[n + 1];
    int e = e0;
    for (; e + 4 <= e1; e += 4) {
        int c0 = col[e], c1 = col[e + 1], c2 = col[e + 2], c3 = col[e + 3];
        float w0 = wgt[e], w1 = wgt[e + 1], w2 = wgt[e + 2], w3 = wgt[e + 3];
        uint32 u0 = XWu[(size_t)c0 * 64 + lane];
        uint32 u1 = XWu[(size_t)c1 * 64 + lane];
        uint32 u2 = XWu[(size_t)c2 * 64 + lane];
        uint32 u3 = XWu[(size_t)c3 * 64 + lane];
        ax = fmaf(w0, blo(u0), ax); ay = fmaf(w0, bhi(u0), ay);
        ax = fmaf(w1, blo(u1), ax); ay = fmaf(w1, bhi(u1), ay);
        ax = fmaf(w2, blo(u2), ax); ay = fmaf(w2, bhi(u2), ay);
        ax = fmaf(w3, blo(u3), ax); ay = fmaf(w3, bhi(u3), ay);
    }
    for (; e < e1; ++e) {
        int c = col[e];
        float w = wgt[e];
        uint32 u = XWu[(size_t)c * 64 + lane];
        ax = fmaf(w, blo(u), ax); ay = fmaf(w, bhi(u), ay);
    }
    float2 bb = ((const float2*)bias)[lane];
    float hx = fmaxf(ax + bb.x, 0.f);
    float hy = fmaxf(ay + bb.y, 0.f);
    float2 wf = ((const float2*)Wfc)[lane];
    float s = hx * wf.x + hy * wf.y;
    for (int d = 32; d > 0; d >>= 1) s += __shfl_down(s, d, 64);
    if (lane == 0) nodeS[n] = s;
}

// ---------------- segment mean over sorted batch + bias (one block per graph) ----------------
__device__ inline int lower_bound_dev(const int* a, int n, int key) {
    int lo = 0, hi = n;
    while (lo < hi) {
        int mid = (lo + hi) >> 1;
        if (a[mid] < key) lo = mid + 1; else hi = mid;
    }
    return lo;
}

__global__ __launch_bounds__(256) void k_pool(const float* __restrict__ nodeS, const int* __restrict__ batch,
                                              const float* __restrict__ bfc, float* __restrict__ out) {
    int g = blockIdx.x;
    int t = threadIdx.x;
    int lo = lower_bound_dev(batch, N_NODES, g);
    int hi = lower_bound_dev(batch, N_NODES, g + 1);
    float s = 0.f;
    for (int i = lo + t; i < hi; i += 256) s += nodeS[i];
    for (int d = 32; d > 0; d >>= 1) s += __shfl_down(s, d, 64);
    __shared__ float ws[4];
    int lane = t & 63, w = t >> 6;
    if (lane == 0) ws[w] = s;
    __syncthreads();
    if (t == 0) {
        float tot = ws[0] + ws[1] + ws[2] + ws[3];
        float cnt = (float)(hi - lo);
        out[g] = tot / fmaxf(cnt, 1.0f) + bfc[0];
    }
}

// ---------------- launch ----------------
extern "C" void kernel_launch(void* const* d_in, const int* in_sizes, int n_in,
                              void* d_out, int out_size, void* d_ws, size_t ws_size,
                              hipStream_t stream) {
    const float* x    = (const float*)d_in[0];
    const int*   ei   = (const int*)d_in[1];     // [2, E] : row0 = src, row1 = dst
    const int*   batch= (const int*)d_in[2];
    const float* W1   = (const float*)d_in[3];
    const float* b1   = (const float*)d_in[4];
    const float* W2   = (const float*)d_in[5];
    const float* b2   = (const float*)d_in[6];
    const float* W3   = (const float*)d_in[7];
    const float* b3   = (const float*)d_in[8];
    const float* Wfc  = (const float*)d_in[9];
    const float* bfc  = (const float*)d_in[10];
    float* out = (float*)d_out;

    const int* src = ei;
    const int* dst = ei + N_EDGES;

    // carve workspace (256B-aligned)
    char* p = (char*)d_ws;
    auto carve = [&](size_t bytes) { void* r = (void*)p; p += (bytes + 255) & ~(size_t)255; return r; };
    int*   counts    = (int*)  carve(sizeof(int)   * N_NODES);
    float* dinv      = (float*)carve(sizeof(float) * N_NODES);
    int*   offsets   = (int*)  carve(sizeof(int)   * (N_NODES + 1));
    int*   cursor    = (int*)  carve(sizeof(int)   * N_NODES);
    int*   col       = (int*)  carve(sizeof(int)   * N_EDGES);
    float* wgt       = (float*)carve(sizeof(float) * N_EDGES);
    unsigned short* xb = (unsigned short*)carve(sizeof(short) * (size_t)N_NODES * NFEAT);
    unsigned short* XW = (unsigned short*)carve(sizeof(short) * (size_t)N_NODES * NFEAT);
    unsigned short* H  = (unsigned short*)carve(sizeof(short) * (size_t)N_NODES * NFEAT);
    unsigned short* WT = (unsigned short*)carve(sizeof(short) * 3 * NFEAT * NFEAT);
    float* nodeS     = (float*)carve(sizeof(float) * N_NODES);
    int*   blockSums = (int*)  carve(sizeof(int)   * SCAN_BLOCKS);
    int*   blockOffs = (int*)  carve(sizeof(int)   * SCAN_BLOCKS);

    const int nodeBlocks = (N_NODES + 255) / 256;            // 391
    const int edgeBlocks = (N_EDGES + 255) / 256;            // 6250
    const int waveNodeBlocks = (N_NODES * 64 + 255) / 256;   // 25000
    const int gemmBlocks = (N_NODES + 63) / 64;              // 1563

    k_init<<<nodeBlocks, 256, 0, stream>>>(counts);
    k_hist<<<edgeBlocks, 256, 0, stream>>>(dst, counts);
    k_dinv<<<nodeBlocks, 256, 0, stream>>>(counts, dinv);
    k_scan_partial<<<SCAN_BLOCKS, 256, 0, stream>>>(counts, blockSums);
    k_scan_blocksums<<<1, 1, 0, stream>>>(blockSums, blockOffs, offsets);
    k_scan_final<<<SCAN_BLOCKS, 256, 0, stream>>>(counts, blockOffs, offsets, cursor);
    k_fill<<<edgeBlocks, 256, 0, stream>>>(src, dst, dinv, cursor, col, wgt);

    k_cast<<<4096, 256, 0, stream>>>(x, xb);
    k_castw<<<(3 * NFEAT * NFEAT + 255) / 256, 256, 0, stream>>>(W1, W2, W3, WT);

    // layer 1
    k_gemm<<<gemmBlocks, 256, 0, stream>>>(xb, WT, XW, N_NODES);
    k_agg<<<waveNodeBlocks, 256, 0, stream>>>((const uint32*)XW, col, wgt, offsets, dinv, b1, (uint32*)H);
    // layer 2
    k_gemm<<<gemmBlocks, 256, 0, stream>>>(H, WT + NFEAT * NFEAT, XW, N_NODES);
    k_agg<<<waveNodeBlocks, 256, 0, stream>>>((const uint32*)XW, col, wgt, offsets, dinv, b2, (uint32*)H);
    // layer 3
    k_gemm<<<gemmBlocks, 256, 0, stream>>>(H, WT + 2 * NFEAT * NFEAT, XW, N_NODES);
    k_agg_fc<<<waveNodeBlocks, 256, 0, stream>>>((const uint32*)XW, col, wgt, offsets, dinv, b3, Wfc, nodeS);

    k_pool<<<N_GRAPHS, 256, 0, stream>>>(nodeS, batch, bfc, out);
}

// Round 4
// 559.763 us; speedup vs baseline: 1.9478x; 1.0515x over previous
//
#include <hip/hip_runtime.h>

#define N_NODES   100000
#define N_EDGES   1600000
#define NFEAT     128
#define N_GRAPHS  1024

#define SCAN_CHUNK  1024
#define SCAN_BLOCKS ((N_NODES + SCAN_CHUNK - 1) / SCAN_CHUNK)   // 98

typedef unsigned int uint32;
typedef __attribute__((ext_vector_type(8))) short short8;   // 8 bf16 (4 VGPRs)
typedef __attribute__((ext_vector_type(4))) float f32x4;

// fp32 -> bf16 bits, round-to-nearest-even (finite inputs)
__device__ inline unsigned short f2b(float f) {
    uint32 x = __float_as_uint(f);
    uint32 r = x + 0x7fffu + ((x >> 16) & 1u);
    return (unsigned short)(r >> 16);
}
__device__ inline float blo(uint32 u) { return __uint_as_float(u << 16); }
__device__ inline float bhi(uint32 u) { return __uint_as_float(u & 0xffff0000u); }

// ---------------- init: zero degree counts ----------------
__global__ __launch_bounds__(256) void k_init(int* counts) {
    int i = blockIdx.x * blockDim.x + threadIdx.x;
    if (i < N_NODES) counts[i] = 0;
}

// ---------------- in-degree histogram over dst ----------------
__global__ __launch_bounds__(256) void k_hist(const int* __restrict__ dst, int* counts) {
    int e = blockIdx.x * blockDim.x + threadIdx.x;
    if (e < N_EDGES) atomicAdd(&counts[dst[e]], 1);
}

// ---------------- deg^{-1/2} (self-loop makes deg >= 1) ----------------
__global__ __launch_bounds__(256) void k_dinv(const int* __restrict__ counts, float* dinv) {
    int n = blockIdx.x * blockDim.x + threadIdx.x;
    if (n < N_NODES) dinv[n] = rsqrtf((float)(counts[n] + 1));
}

// ---------------- exclusive scan of counts -> offsets ----------------
__global__ __launch_bounds__(256) void k_scan_partial(const int* __restrict__ counts, int* blockSums) {
    int base = blockIdx.x * SCAN_CHUNK;
    int t = threadIdx.x;
    int s = 0;
    for (int i = t; i < SCAN_CHUNK; i += 256) {
        int idx = base + i;
        if (idx < N_NODES) s += counts[idx];
    }
    for (int d = 32; d > 0; d >>= 1) s += __shfl_down(s, d, 64);
    __shared__ int lds[4];
    int lane = t & 63, w = t >> 6;
    if (lane == 0) lds[w] = s;
    __syncthreads();
    if (t == 0) blockSums[blockIdx.x] = lds[0] + lds[1] + lds[2] + lds[3];
}

__global__ void k_scan_blocksums(int* blockSums, int* blockOffs, int* offsets) {
    int run = 0;
    for (int b = 0; b < SCAN_BLOCKS; ++b) { blockOffs[b] = run; run += blockSums[b]; }
    offsets[N_NODES] = run;   // == N_EDGES
}

__global__ __launch_bounds__(256) void k_scan_final(const int* __restrict__ counts,
                                                    const int* __restrict__ blockOffs,
                                                    int* offsets, int* cursor) {
    int base = blockIdx.x * SCAN_CHUNK;
    int t = threadIdx.x;
    int c[4];
    int ts = 0;
    #pragma unroll
    for (int i = 0; i < 4; ++i) {
        int idx = base + 4 * t + i;
        c[i] = (idx < N_NODES) ? counts[idx] : 0;
        ts += c[i];
    }
    int lane = t & 63, w = t >> 6;
    int inc = ts;
    #pragma unroll
    for (int d = 1; d < 64; d <<= 1) {
        int v = __shfl_up(inc, d, 64);
        if (lane >= d) inc += v;
    }
    __shared__ int wsum[4];
    if (lane == 63) wsum[w] = inc;
    __syncthreads();
    int wpre = 0;
    for (int i = 0; i < w; ++i) wpre += wsum[i];
    int run = blockOffs[blockIdx.x] + wpre + (inc - ts);
    #pragma unroll
    for (int i = 0; i < 4; ++i) {
        int idx = base + 4 * t + i;
        if (idx < N_NODES) { offsets[idx] = run; cursor[idx] = run; }
        run += c[i];
    }
}

// ---------------- CSR fill: single 4B scatter per edge (no wgt array) ----------------
__global__ __launch_bounds__(256) void k_fill(const int* __restrict__ src, const int* __restrict__ dst,
                                              int* cursor, int* col) {
    int e = blockIdx.x * blockDim.x + threadIdx.x;
    if (e < N_EDGES) {
        int s = src[e], d = dst[e];
        int p = atomicAdd(&cursor[d], 1);
        col[p] = s;
    }
}

// ---------------- cast + transpose W1,W2,W3 -> WT bf16 [layer][n][k] ----------------
__global__ __launch_bounds__(256) void k_castw(const float* __restrict__ W1, const float* __restrict__ W2,
                                               const float* __restrict__ W3, unsigned short* __restrict__ WT) {
    int i = blockIdx.x * blockDim.x + threadIdx.x;   // 3*16384
    if (i >= 3 * NFEAT * NFEAT) return;
    int l = i >> 14;
    int j = i & 16383;
    int n = j >> 7;
    int k = j & 127;
    const float* W = (l == 0) ? W1 : (l == 1) ? W2 : W3;
    WT[i] = f2b(W[k * NFEAT + n]);   // WT[l][n*128+k] = W[k][n]
}

// ---------------- bf16 MFMA GEMM: C[M,128] = A[M,128] @ W ----------------
// A bf16 row-major, WT bf16 [n][k], C bf16 row-major.
// Block = 256 thr = 4 waves, 64 rows/block; wave computes 16 rows x 128 cols.
#define WT_STRIDE 136
__global__ __launch_bounds__(256) void k_gemm(const unsigned short* __restrict__ A,
                                              const unsigned short* __restrict__ WTl,
                                              unsigned short* __restrict__ C, int M) {
    __shared__ unsigned short sWT[NFEAT * WT_STRIDE];   // 34 KB
    int t = threadIdx.x;
    for (int i = t; i < NFEAT * 16; i += 256) {
        int n = i >> 4, c = i & 15;
        *(float4*)(sWT + n * WT_STRIDE + c * 8) = ((const float4*)WTl)[i];
    }
    int wave = t >> 6, lane = t & 63;
    int m0 = blockIdx.x * 64 + wave * 16;
    int mRow = m0 + (lane & 15);
    if (mRow >= M) mRow = M - 1;
    int kg = lane >> 4;
    const short8* Ap = (const short8*)(A + (size_t)mRow * NFEAT + kg * 8);
    short8 a0 = Ap[0];
    short8 a1 = Ap[4];
    short8 a2 = Ap[8];
    short8 a3 = Ap[12];
    __syncthreads();

    f32x4 acc[8];
    #pragma unroll
    for (int nt = 0; nt < 8; ++nt) acc[nt] = (f32x4){0.f, 0.f, 0.f, 0.f};

    #pragma unroll
    for (int nt = 0; nt < 8; ++nt) {
        int n = nt * 16 + (lane & 15);
        const short8* Bp = (const short8*)(sWT + n * WT_STRIDE + kg * 8);
        short8 b0 = Bp[0];
        short8 b1 = Bp[4];
        short8 b2 = Bp[8];
        short8 b3 = Bp[12];
        acc[nt] = __builtin_amdgcn_mfma_f32_16x16x32_bf16(a0, b0, acc[nt], 0, 0, 0);
        acc[nt] = __builtin_amdgcn_mfma_f32_16x16x32_bf16(a1, b1, acc[nt], 0, 0, 0);
        acc[nt] = __builtin_amdgcn_mfma_f32_16x16x32_bf16(a2, b2, acc[nt], 0, 0, 0);
        acc[nt] = __builtin_amdgcn_mfma_f32_16x16x32_bf16(a3, b3, acc[nt], 0, 0, 0);
    }

    int colBase = lane & 15;
    #pragma unroll
    for (int r = 0; r < 4; ++r) {
        int gr = m0 + kg * 4 + r;
        if (gr < M) {
            unsigned short* Cp = C + (size_t)gr * NFEAT + colBase;
            #pragma unroll
            for (int nt = 0; nt < 8; ++nt) Cp[nt * 16] = f2b(acc[nt][r]);
        }
    }
}

// ---------------- same GEMM but A is fp32 (layer 1: fuses the x->bf16 cast) ----------------
__device__ inline short8 cvt8(const float* p) {
    float4 v0 = ((const float4*)p)[0];
    float4 v1 = ((const float4*)p)[1];
    short8 r;
    r[0] = (short)f2b(v0.x); r[1] = (short)f2b(v0.y);
    r[2] = (short)f2b(v0.z); r[3] = (short)f2b(v0.w);
    r[4] = (short)f2b(v1.x); r[5] = (short)f2b(v1.y);
    r[6] = (short)f2b(v1.z); r[7] = (short)f2b(v1.w);
    return r;
}

__global__ __launch_bounds__(256) void k_gemm_x(const float* __restrict__ A,
                                                const unsigned short* __restrict__ WTl,
                                                unsigned short* __restrict__ C, int M) {
    __shared__ unsigned short sWT[NFEAT * WT_STRIDE];   // 34 KB
    int t = threadIdx.x;
    for (int i = t; i < NFEAT * 16; i += 256) {
        int n = i >> 4, c = i & 15;
        *(float4*)(sWT + n * WT_STRIDE + c * 8) = ((const float4*)WTl)[i];
    }
    int wave = t >> 6, lane = t & 63;
    int m0 = blockIdx.x * 64 + wave * 16;
    int mRow = m0 + (lane & 15);
    if (mRow >= M) mRow = M - 1;
    int kg = lane >> 4;
    const float* Ap = A + (size_t)mRow * NFEAT + kg * 8;
    short8 a0 = cvt8(Ap);
    short8 a1 = cvt8(Ap + 32);
    short8 a2 = cvt8(Ap + 64);
    short8 a3 = cvt8(Ap + 96);
    __syncthreads();

    f32x4 acc[8];
    #pragma unroll
    for (int nt = 0; nt < 8; ++nt) acc[nt] = (f32x4){0.f, 0.f, 0.f, 0.f};

    #pragma unroll
    for (int nt = 0; nt < 8; ++nt) {
        int n = nt * 16 + (lane & 15);
        const short8* Bp = (const short8*)(sWT + n * WT_STRIDE + kg * 8);
        short8 b0 = Bp[0];
        short8 b1 = Bp[4];
        short8 b2 = Bp[8];
        short8 b3 = Bp[12];
        acc[nt] = __builtin_amdgcn_mfma_f32_16x16x32_bf16(a0, b0, acc[nt], 0, 0, 0);
        acc[nt] = __builtin_amdgcn_mfma_f32_16x16x32_bf16(a1, b1, acc[nt], 0, 0, 0);
        acc[nt] = __builtin_amdgcn_mfma_f32_16x16x32_bf16(a2, b2, acc[nt], 0, 0, 0);
        acc[nt] = __builtin_amdgcn_mfma_f32_16x16x32_bf16(a3, b3, acc[nt], 0, 0, 0);
    }

    int colBase = lane & 15;
    #pragma unroll
    for (int r = 0; r < 4; ++r) {
        int gr = m0 + kg * 4 + r;
        if (gr < M) {
            unsigned short* Cp = C + (size_t)gr * NFEAT + colBase;
            #pragma unroll
            for (int nt = 0; nt < 8; ++nt) Cp[nt * 16] = f2b(acc[nt][r]);
        }
    }
}

// ---------------- aggregation core (bf16 rows, weights from dinv, unroll x8) ----------------
// H[n] = relu( dinv[n]^2*XW[n] + sum_e dinv[n]*dinv[col]*XW[col] + b )
#define AGG_BODY \
    float dn = dinv[n]; \
    uint32 v = XWu[(size_t)n * 64 + lane]; \
    float ax = dn * dn * blo(v); \
    float ay = dn * dn * bhi(v); \
    int e0 = off[n], e1 = off[n + 1]; \
    int e = e0; \
    for (; e + 8 <= e1; e += 8) { \
        int c0 = col[e],     c1 = col[e + 1], c2 = col[e + 2], c3 = col[e + 3]; \
        int c4 = col[e + 4], c5 = col[e + 5], c6 = col[e + 6], c7 = col[e + 7]; \
        float w0 = dn * dinv[c0], w1 = dn * dinv[c1], w2 = dn * dinv[c2], w3 = dn * dinv[c3]; \
        float w4 = dn * dinv[c4], w5 = dn * dinv[c5], w6 = dn * dinv[c6], w7 = dn * dinv[c7]; \
        uint32 u0 = XWu[(size_t)c0 * 64 + lane]; \
        uint32 u1 = XWu[(size_t)c1 * 64 + lane]; \
        uint32 u2 = XWu[(size_t)c2 * 64 + lane]; \
        uint32 u3 = XWu[(size_t)c3 * 64 + lane]; \
        uint32 u4 = XWu[(size_t)c4 * 64 + lane]; \
        uint32 u5 = XWu[(size_t)c5 * 64 + lane]; \
        uint32 u6 = XWu[(size_t)c6 * 64 + lane]; \
        uint32 u7 = XWu[(size_t)c7 * 64 + lane]; \
        ax = fmaf(w0, blo(u0), ax); ay = fmaf(w0, bhi(u0), ay); \
        ax = fmaf(w1, blo(u1), ax); ay = fmaf(w1, bhi(u1), ay); \
        ax = fmaf(w2, blo(u2), ax); ay = fmaf(w2, bhi(u2), ay); \
        ax = fmaf(w3, blo(u3), ax); ay = fmaf(w3, bhi(u3), ay); \
        ax = fmaf(w4, blo(u4), ax); ay = fmaf(w4, bhi(u4), ay); \
        ax = fmaf(w5, blo(u5), ax); ay = fmaf(w5, bhi(u5), ay); \
        ax = fmaf(w6, blo(u6), ax); ay = fmaf(w6, bhi(u6), ay); \
        ax = fmaf(w7, blo(u7), ax); ay = fmaf(w7, bhi(u7), ay); \
    } \
    for (; e + 2 <= e1; e += 2) { \
        int c0 = col[e], c1 = col[e + 1]; \
        float w0 = dn * dinv[c0], w1 = dn * dinv[c1]; \
        uint32 u0 = XWu[(size_t)c0 * 64 + lane]; \
        uint32 u1 = XWu[(size_t)c1 * 64 + lane]; \
        ax = fmaf(w0, blo(u0), ax); ay = fmaf(w0, bhi(u0), ay); \
        ax = fmaf(w1, blo(u1), ax); ay = fmaf(w1, bhi(u1), ay); \
    } \
    if (e < e1) { \
        int c = col[e]; \
        float w = dn * dinv[c]; \
        uint32 u = XWu[(size_t)c * 64 + lane]; \
        ax = fmaf(w, blo(u), ax); ay = fmaf(w, bhi(u), ay); \
    }

__global__ __launch_bounds__(256) void k_agg(const uint32* __restrict__ XWu, const int* __restrict__ col,
                                             const int* __restrict__ off, const float* __restrict__ dinv,
                                             const float* __restrict__ bias, uint32* __restrict__ Hu) {
    int wid = (blockIdx.x * blockDim.x + threadIdx.x) >> 6;
    int lane = threadIdx.x & 63;
    if (wid >= N_NODES) return;
    int n = wid;
    AGG_BODY
    float2 bb = ((const float2*)bias)[lane];
    float ox = fmaxf(ax + bb.x, 0.f);
    float oy = fmaxf(ay + bb.y, 0.f);
    Hu[(size_t)n * 64 + lane] = (uint32)f2b(ox) | ((uint32)f2b(oy) << 16);
}

// ---------------- layer-3 aggregation + relu + FC dot -> per-node scalar ----------------
__global__ __launch_bounds__(256) void k_agg_fc(const uint32* __restrict__ XWu, const int* __restrict__ col,
                                                const int* __restrict__ off, const float* __restrict__ dinv,
                                                const float* __restrict__ bias, const float* __restrict__ Wfc,
                                                float* __restrict__ nodeS) {
    int wid = (blockIdx.x * blockDim.x + threadIdx.x) >> 6;
    int lane = threadIdx.x & 63;
    if (wid >= N_NODES) return;
    int n = wid;
    AGG_BODY
    float2 bb = ((const float2*)bias)[lane];
    float hx = fmaxf(ax + bb.x, 0.f);
    float hy = fmaxf(ay + bb.y, 0.f);
    float2 wf = ((const float2*)Wfc)[lane];
    float s = hx * wf.x + hy * wf.y;
    for (int d = 32; d > 0; d >>= 1) s += __shfl_down(s, d, 64);
    if (lane == 0) nodeS[n] = s;
}

// ---------------- segment mean over sorted batch + bias (one block per graph) ----------------
__device__ inline int lower_bound_dev(const int* a, int n, int key) {
    int lo = 0, hi = n;
    while (lo < hi) {
        int mid = (lo + hi) >> 1;
        if (a[mid] < key) lo = mid + 1; else hi = mid;
    }
    return lo;
}

__global__ __launch_bounds__(256) void k_pool(const float* __restrict__ nodeS, const int* __restrict__ batch,
                                              const float* __restrict__ bfc, float* __restrict__ out) {
    int g = blockIdx.x;
    int t = threadIdx.x;
    int lo = lower_bound_dev(batch, N_NODES, g);
    int hi = lower_bound_dev(batch, N_NODES, g + 1);
    float s = 0.f;
    for (int i = lo + t; i < hi; i += 256) s += nodeS[i];
    for (int d = 32; d > 0; d >>= 1) s += __shfl_down(s, d, 64);
    __shared__ float ws[4];
    int lane = t & 63, w = t >> 6;
    if (lane == 0) ws[w] = s;
    __syncthreads();
    if (t == 0) {
        float tot = ws[0] + ws[1] + ws[2] + ws[3];
        float cnt = (float)(hi - lo);
        out[g] = tot / fmaxf(cnt, 1.0f) + bfc[0];
    }
}

// ---------------- launch ----------------
extern "C" void kernel_launch(void* const* d_in, const int* in_sizes, int n_in,
                              void* d_out, int out_size, void* d_ws, size_t ws_size,
                              hipStream_t stream) {
    const float* x    = (const float*)d_in[0];
    const int*   ei   = (const int*)d_in[1];     // [2, E] : row0 = src, row1 = dst
    const int*   batch= (const int*)d_in[2];
    const float* W1   = (const float*)d_in[3];
    const float* b1   = (const float*)d_in[4];
    const float* W2   = (const float*)d_in[5];
    const float* b2   = (const float*)d_in[6];
    const float* W3   = (const float*)d_in[7];
    const float* b3   = (const float*)d_in[8];
    const float* Wfc  = (const float*)d_in[9];
    const float* bfc  = (const float*)d_in[10];
    float* out = (float*)d_out;

    const int* src = ei;
    const int* dst = ei + N_EDGES;

    // carve workspace (256B-aligned)
    char* p = (char*)d_ws;
    auto carve = [&](size_t bytes) { void* r = (void*)p; p += (bytes + 255) & ~(size_t)255; return r; };
    int*   counts    = (int*)  carve(sizeof(int)   * N_NODES);
    float* dinv      = (float*)carve(sizeof(float) * N_NODES);
    int*   offsets   = (int*)  carve(sizeof(int)   * (N_NODES + 1));
    int*   cursor    = (int*)  carve(sizeof(int)   * N_NODES);
    int*   col       = (int*)  carve(sizeof(int)   * N_EDGES);
    unsigned short* XW = (unsigned short*)carve(sizeof(short) * (size_t)N_NODES * NFEAT);
    unsigned short* H  = (unsigned short*)carve(sizeof(short) * (size_t)N_NODES * NFEAT);
    unsigned short* WT = (unsigned short*)carve(sizeof(short) * 3 * NFEAT * NFEAT);
    float* nodeS     = (float*)carve(sizeof(float) * N_NODES);
    int*   blockSums = (int*)  carve(sizeof(int)   * SCAN_BLOCKS);
    int*   blockOffs = (int*)  carve(sizeof(int)   * SCAN_BLOCKS);

    const int nodeBlocks = (N_NODES + 255) / 256;            // 391
    const int edgeBlocks = (N_EDGES + 255) / 256;            // 6250
    const int waveNodeBlocks = (N_NODES * 64 + 255) / 256;   // 25000
    const int gemmBlocks = (N_NODES + 63) / 64;              // 1563

    k_init<<<nodeBlocks, 256, 0, stream>>>(counts);
    k_hist<<<edgeBlocks, 256, 0, stream>>>(dst, counts);
    k_dinv<<<nodeBlocks, 256, 0, stream>>>(counts, dinv);
    k_scan_partial<<<SCAN_BLOCKS, 256, 0, stream>>>(counts, blockSums);
    k_scan_blocksums<<<1, 1, 0, stream>>>(blockSums, blockOffs, offsets);
    k_scan_final<<<SCAN_BLOCKS, 256, 0, stream>>>(counts, blockOffs, offsets, cursor);
    k_fill<<<edgeBlocks, 256, 0, stream>>>(src, dst, cursor, col);

    k_castw<<<(3 * NFEAT * NFEAT + 255) / 256, 256, 0, stream>>>(W1, W2, W3, WT);

    // layer 1 (cast fused into GEMM A-load)
    k_gemm_x<<<gemmBlocks, 256, 0, stream>>>(x, WT, XW, N_NODES);
    k_agg<<<waveNodeBlocks, 256, 0, stream>>>((const uint32*)XW, col, offsets, dinv, b1, (uint32*)H);
    // layer 2
    k_gemm<<<gemmBlocks, 256, 0, stream>>>(H, WT + NFEAT * NFEAT, XW, N_NODES);
    k_agg<<<waveNodeBlocks, 256, 0, stream>>>((const uint32*)XW, col, offsets, dinv, b2, (uint32*)H);
    // layer 3
    k_gemm<<<gemmBlocks, 256, 0, stream>>>(H, WT + 2 * NFEAT * NFEAT, XW, N_NODES);
    k_agg_fc<<<waveNodeBlocks, 256, 0, stream>>>((const uint32*)XW, col, offsets, dinv, b3, Wfc, nodeS);

    k_pool<<<N_GRAPHS, 256, 0, stream>>>(nodeS, batch, bfc, out);
}

// Round 5
// 440.791 us; speedup vs baseline: 2.4735x; 1.2699x over previous
//
#include <hip/hip_runtime.h>

#define N_NODES   100000
#define N_EDGES   1600000
#define NFEAT     128
#define N_GRAPHS  1024

// ---- bucketed CSR build ----
#define BSHIFT  6
#define NBUCK   1563                 // ceil(100000 / 64)
#define NSUB    8                    // sub-buckets (XCD-heuristic partition)
#define SUBCAP  256                  // mean 128, +11 sigma headroom
#define CURSTRIDE 16                 // one cursor per 64B line

typedef unsigned int uint32;
typedef __attribute__((ext_vector_type(8))) short short8;   // 8 bf16 (4 VGPRs)
typedef __attribute__((ext_vector_type(4))) float f32x4;

// fp32 -> bf16 bits, round-to-nearest-even (finite inputs)
__device__ inline unsigned short f2b(float f) {
    uint32 x = __float_as_uint(f);
    uint32 r = x + 0x7fffu + ((x >> 16) & 1u);
    return (unsigned short)(r >> 16);
}
__device__ inline float blo(uint32 u) { return __uint_as_float(u << 16); }
__device__ inline float bhi(uint32 u) { return __uint_as_float(u & 0xffff0000u); }

// ---------------- phase 1: scatter edges into (bucket, sub) append regions ----------------
__global__ __launch_bounds__(256) void k_scatter(const int* __restrict__ src, const int* __restrict__ dst,
                                                 int* __restrict__ cur, uint32* __restrict__ bbuf) {
    int e = blockIdx.x * 256 + threadIdx.x;
    int sub = blockIdx.x & (NSUB - 1);
    if (e < N_EDGES) {
        int s = src[e], d = dst[e];
        int b = d >> BSHIFT;
        int slot = (b << 3) | sub;
        int p = atomicAdd(&cur[slot * CURSTRIDE], 1);
        if (p < SUBCAP)
            bbuf[slot * SUBCAP + p] = (uint32)(((d & 63) << 17) | s);
    }
}

// ---------------- exclusive scan of bucket totals -> bucketBase, + offsets[N] ----------------
__global__ __launch_bounds__(256) void k_bucketscan(const int* __restrict__ cur, int* __restrict__ bucketBase,
                                                    int* __restrict__ offsets) {
    __shared__ int wsum[4];
    int t = threadIdx.x;
    int v[7];
    int ts = 0;
    #pragma unroll
    for (int i = 0; i < 7; ++i) {
        int b = t * 7 + i;
        int sz = 0;
        if (b < NBUCK) {
            #pragma unroll
            for (int s = 0; s < NSUB; ++s) {
                int c = cur[((b << 3) | s) * CURSTRIDE];
                sz += (c < SUBCAP) ? c : SUBCAP;
            }
        }
        v[i] = sz;
        ts += sz;
    }
    int lane = t & 63, w = t >> 6;
    int inc = ts;
    #pragma unroll
    for (int d = 1; d < 64; d <<= 1) {
        int u = __shfl_up(inc, d, 64);
        if (lane >= d) inc += u;
    }
    if (lane == 63) wsum[w] = inc;
    __syncthreads();
    int wpre = 0;
    for (int i = 0; i < w; ++i) wpre += wsum[i];
    int run = wpre + inc - ts;
    #pragma unroll
    for (int i = 0; i < 7; ++i) {
        int b = t * 7 + i;
        if (b < NBUCK) bucketBase[b] = run;
        run += v[i];
    }
    if (t == 255) offsets[N_NODES] = run;   // == N_EDGES
}

// ---------------- phase 2: per-bucket local sort -> coalesced CSR + dinv + offsets ----------------
__global__ __launch_bounds__(256) void k_build(const uint32* __restrict__ bbuf, const int* __restrict__ cur,
                                               const int* __restrict__ bucketBase, int* __restrict__ col,
                                               int* __restrict__ offsets, float* __restrict__ dinv) {
    int b = blockIdx.x;
    __shared__ uint32 ebuf[NSUB * SUBCAP];    // 8 KB
    __shared__ int sorted[NSUB * SUBCAP];     // 8 KB
    __shared__ int hist[64], lcur[64];
    __shared__ int subOff[NSUB + 1];
    int t = threadIdx.x;
    if (t == 0) {
        int run = 0;
        #pragma unroll
        for (int s = 0; s < NSUB; ++s) {
            subOff[s] = run;
            int c = cur[((b << 3) | s) * CURSTRIDE];
            run += (c < SUBCAP) ? c : SUBCAP;
        }
        subOff[NSUB] = run;
    }
    if (t < 64) hist[t] = 0;
    __syncthreads();
    int cnt = subOff[NSUB];
    #pragma unroll
    for (int s = 0; s < NSUB; ++s) {
        int n = subOff[s + 1] - subOff[s];
        const uint32* p = bbuf + ((b << 3) | s) * SUBCAP;
        for (int i = t; i < n; i += 256) ebuf[subOff[s] + i] = p[i];
    }
    __syncthreads();
    for (int i = t; i < cnt; i += 256) atomicAdd(&hist[ebuf[i] >> 17], 1);
    __syncthreads();
    int nb = b << BSHIFT;
    if (t < 64) {   // wave 0: scan 64 counts, emit offsets + dinv
        int c = hist[t];
        int inc = c;
        #pragma unroll
        for (int d = 1; d < 64; d <<= 1) {
            int u = __shfl_up(inc, d, 64);
            if (t >= d) inc += u;
        }
        int excl = inc - c;
        lcur[t] = excl;
        int node = nb + t;
        if (node < N_NODES) {
            offsets[node] = bucketBase[b] + excl;
            dinv[node] = rsqrtf((float)(c + 1));
        }
    }
    __syncthreads();
    for (int i = t; i < cnt; i += 256) {
        uint32 p = ebuf[i];
        int lp = atomicAdd(&lcur[p >> 17], 1);
        sorted[lp] = (int)(p & 0x1FFFF);
    }
    __syncthreads();
    int base = bucketBase[b];
    for (int i = t; i < cnt; i += 256) col[base + i] = sorted[i];
}

// ---------------- cast + transpose W1,W2,W3 -> WT bf16 [layer][n][k] ----------------
__global__ __launch_bounds__(256) void k_castw(const float* __restrict__ W1, const float* __restrict__ W2,
                                               const float* __restrict__ W3, unsigned short* __restrict__ WT) {
    int i = blockIdx.x * blockDim.x + threadIdx.x;   // 3*16384
    if (i >= 3 * NFEAT * NFEAT) return;
    int l = i >> 14;
    int j = i & 16383;
    int n = j >> 7;
    int k = j & 127;
    const float* W = (l == 0) ? W1 : (l == 1) ? W2 : W3;
    WT[i] = f2b(W[k * NFEAT + n]);   // WT[l][n*128+k] = W[k][n]
}

// ---------------- bf16 MFMA GEMM: C[M,128] = A[M,128] @ W ----------------
#define WT_STRIDE 136
__global__ __launch_bounds__(256) void k_gemm(const unsigned short* __restrict__ A,
                                              const unsigned short* __restrict__ WTl,
                                              unsigned short* __restrict__ C, int M) {
    __shared__ unsigned short sWT[NFEAT * WT_STRIDE];   // 34 KB
    int t = threadIdx.x;
    for (int i = t; i < NFEAT * 16; i += 256) {
        int n = i >> 4, c = i & 15;
        *(float4*)(sWT + n * WT_STRIDE + c * 8) = ((const float4*)WTl)[i];
    }
    int wave = t >> 6, lane = t & 63;
    int m0 = blockIdx.x * 64 + wave * 16;
    int mRow = m0 + (lane & 15);
    if (mRow >= M) mRow = M - 1;
    int kg = lane >> 4;
    const short8* Ap = (const short8*)(A + (size_t)mRow * NFEAT + kg * 8);
    short8 a0 = Ap[0];
    short8 a1 = Ap[4];
    short8 a2 = Ap[8];
    short8 a3 = Ap[12];
    __syncthreads();

    f32x4 acc[8];
    #pragma unroll
    for (int nt = 0; nt < 8; ++nt) acc[nt] = (f32x4){0.f, 0.f, 0.f, 0.f};

    #pragma unroll
    for (int nt = 0; nt < 8; ++nt) {
        int n = nt * 16 + (lane & 15);
        const short8* Bp = (const short8*)(sWT + n * WT_STRIDE + kg * 8);
        short8 b0 = Bp[0];
        short8 b1 = Bp[4];
        short8 b2 = Bp[8];
        short8 b3 = Bp[12];
        acc[nt] = __builtin_amdgcn_mfma_f32_16x16x32_bf16(a0, b0, acc[nt], 0, 0, 0);
        acc[nt] = __builtin_amdgcn_mfma_f32_16x16x32_bf16(a1, b1, acc[nt], 0, 0, 0);
        acc[nt] = __builtin_amdgcn_mfma_f32_16x16x32_bf16(a2, b2, acc[nt], 0, 0, 0);
        acc[nt] = __builtin_amdgcn_mfma_f32_16x16x32_bf16(a3, b3, acc[nt], 0, 0, 0);
    }

    int colBase = lane & 15;
    #pragma unroll
    for (int r = 0; r < 4; ++r) {
        int gr = m0 + kg * 4 + r;
        if (gr < M) {
            unsigned short* Cp = C + (size_t)gr * NFEAT + colBase;
            #pragma unroll
            for (int nt = 0; nt < 8; ++nt) Cp[nt * 16] = f2b(acc[nt][r]);
        }
    }
}

// ---------------- same GEMM but A is fp32 (layer 1: fuses the x->bf16 cast) ----------------
__device__ inline short8 cvt8(const float* p) {
    float4 v0 = ((const float4*)p)[0];
    float4 v1 = ((const float4*)p)[1];
    short8 r;
    r[0] = (short)f2b(v0.x); r[1] = (short)f2b(v0.y);
    r[2] = (short)f2b(v0.z); r[3] = (short)f2b(v0.w);
    r[4] = (short)f2b(v1.x); r[5] = (short)f2b(v1.y);
    r[6] = (short)f2b(v1.z); r[7] = (short)f2b(v1.w);
    return r;
}

__global__ __launch_bounds__(256) void k_gemm_x(const float* __restrict__ A,
                                                const unsigned short* __restrict__ WTl,
                                                unsigned short* __restrict__ C, int M) {
    __shared__ unsigned short sWT[NFEAT * WT_STRIDE];   // 34 KB
    int t = threadIdx.x;
    for (int i = t; i < NFEAT * 16; i += 256) {
        int n = i >> 4, c = i & 15;
        *(float4*)(sWT + n * WT_STRIDE + c * 8) = ((const float4*)WTl)[i];
    }
    int wave = t >> 6, lane = t & 63;
    int m0 = blockIdx.x * 64 + wave * 16;
    int mRow = m0 + (lane & 15);
    if (mRow >= M) mRow = M - 1;
    int kg = lane >> 4;
    const float* Ap = A + (size_t)mRow * NFEAT + kg * 8;
    short8 a0 = cvt8(Ap);
    short8 a1 = cvt8(Ap + 32);
    short8 a2 = cvt8(Ap + 64);
    short8 a3 = cvt8(Ap + 96);
    __syncthreads();

    f32x4 acc[8];
    #pragma unroll
    for (int nt = 0; nt < 8; ++nt) acc[nt] = (f32x4){0.f, 0.f, 0.f, 0.f};

    #pragma unroll
    for (int nt = 0; nt < 8; ++nt) {
        int n = nt * 16 + (lane & 15);
        const short8* Bp = (const short8*)(sWT + n * WT_STRIDE + kg * 8);
        short8 b0 = Bp[0];
        short8 b1 = Bp[4];
        short8 b2 = Bp[8];
        short8 b3 = Bp[12];
        acc[nt] = __builtin_amdgcn_mfma_f32_16x16x32_bf16(a0, b0, acc[nt], 0, 0, 0);
        acc[nt] = __builtin_amdgcn_mfma_f32_16x16x32_bf16(a1, b1, acc[nt], 0, 0, 0);
        acc[nt] = __builtin_amdgcn_mfma_f32_16x16x32_bf16(a2, b2, acc[nt], 0, 0, 0);
        acc[nt] = __builtin_amdgcn_mfma_f32_16x16x32_bf16(a3, b3, acc[nt], 0, 0, 0);
    }

    int colBase = lane & 15;
    #pragma unroll
    for (int r = 0; r < 4; ++r) {
        int gr = m0 + kg * 4 + r;
        if (gr < M) {
            unsigned short* Cp = C + (size_t)gr * NFEAT + colBase;
            #pragma unroll
            for (int nt = 0; nt < 8; ++nt) Cp[nt * 16] = f2b(acc[nt][r]);
        }
    }
}

// ---------------- aggregation core (bf16 rows, weights from dinv, unroll x8) ----------------
#define AGG_BODY \
    float dn = dinv[n]; \
    uint32 v = XWu[(size_t)n * 64 + lane]; \
    float ax = dn * dn * blo(v); \
    float ay = dn * dn * bhi(v); \
    int e0 = off[n], e1 = off[n + 1]; \
    int e = e0; \
    for (; e + 8 <= e1; e += 8) { \
        int c0 = col[e],     c1 = col[e + 1], c2 = col[e + 2], c3 = col[e + 3]; \
        int c4 = col[e + 4], c5 = col[e + 5], c6 = col[e + 6], c7 = col[e + 7]; \
        float w0 = dn * dinv[c0], w1 = dn * dinv[c1], w2 = dn * dinv[c2], w3 = dn * dinv[c3]; \
        float w4 = dn * dinv[c4], w5 = dn * dinv[c5], w6 = dn * dinv[c6], w7 = dn * dinv[c7]; \
        uint32 u0 = XWu[(size_t)c0 * 64 + lane]; \
        uint32 u1 = XWu[(size_t)c1 * 64 + lane]; \
        uint32 u2 = XWu[(size_t)c2 * 64 + lane]; \
        uint32 u3 = XWu[(size_t)c3 * 64 + lane]; \
        uint32 u4 = XWu[(size_t)c4 * 64 + lane]; \
        uint32 u5 = XWu[(size_t)c5 * 64 + lane]; \
        uint32 u6 = XWu[(size_t)c6 * 64 + lane]; \
        uint32 u7 = XWu[(size_t)c7 * 64 + lane]; \
        ax = fmaf(w0, blo(u0), ax); ay = fmaf(w0, bhi(u0), ay); \
        ax = fmaf(w1, blo(u1), ax); ay = fmaf(w1, bhi(u1), ay); \
        ax = fmaf(w2, blo(u2), ax); ay = fmaf(w2, bhi(u2), ay); \
        ax = fmaf(w3, blo(u3), ax); ay = fmaf(w3, bhi(u3), ay); \
        ax = fmaf(w4, blo(u4), ax); ay = fmaf(w4, bhi(u4), ay); \
        ax = fmaf(w5, blo(u5), ax); ay = fmaf(w5, bhi(u5), ay); \
        ax = fmaf(w6, blo(u6), ax); ay = fmaf(w6, bhi(u6), ay); \
        ax = fmaf(w7, blo(u7), ax); ay = fmaf(w7, bhi(u7), ay); \
    } \
    for (; e + 2 <= e1; e += 2) { \
        int c0 = col[e], c1 = col[e + 1]; \
        float w0 = dn * dinv[c0], w1 = dn * dinv[c1]; \
        uint32 u0 = XWu[(size_t)c0 * 64 + lane]; \
        uint32 u1 = XWu[(size_t)c1 * 64 + lane]; \
        ax = fmaf(w0, blo(u0), ax); ay = fmaf(w0, bhi(u0), ay); \
        ax = fmaf(w1, blo(u1), ax); ay = fmaf(w1, bhi(u1), ay); \
    } \
    if (e < e1) { \
        int c = col[e]; \
        float w = dn * dinv[c]; \
        uint32 u = XWu[(size_t)c * 64 + lane]; \
        ax = fmaf(w, blo(u), ax); ay = fmaf(w, bhi(u), ay); \
    }

__global__ __launch_bounds__(256) void k_agg(const uint32* __restrict__ XWu, const int* __restrict__ col,
                                             const int* __restrict__ off, const float* __restrict__ dinv,
                                             const float* __restrict__ bias, uint32* __restrict__ Hu) {
    int wid = (blockIdx.x * blockDim.x + threadIdx.x) >> 6;
    int lane = threadIdx.x & 63;
    if (wid >= N_NODES) return;
    int n = wid;
    AGG_BODY
    float2 bb = ((const float2*)bias)[lane];
    float ox = fmaxf(ax + bb.x, 0.f);
    float oy = fmaxf(ay + bb.y, 0.f);
    Hu[(size_t)n * 64 + lane] = (uint32)f2b(ox) | ((uint32)f2b(oy) << 16);
}

// ---------------- layer-3 aggregation + relu + FC dot -> per-node scalar ----------------
__global__ __launch_bounds__(256) void k_agg_fc(const uint32* __restrict__ XWu, const int* __restrict__ col,
                                                const int* __restrict__ off, const float* __restrict__ dinv,
                                                const float* __restrict__ bias, const float* __restrict__ Wfc,
                                                float* __restrict__ nodeS) {
    int wid = (blockIdx.x * blockDim.x + threadIdx.x) >> 6;
    int lane = threadIdx.x & 63;
    if (wid >= N_NODES) return;
    int n = wid;
    AGG_BODY
    float2 bb = ((const float2*)bias)[lane];
    float hx = fmaxf(ax + bb.x, 0.f);
    float hy = fmaxf(ay + bb.y, 0.f);
    float2 wf = ((const float2*)Wfc)[lane];
    float s = hx * wf.x + hy * wf.y;
    for (int d = 32; d > 0; d >>= 1) s += __shfl_down(s, d, 64);
    if (lane == 0) nodeS[n] = s;
}

// ---------------- segment mean over sorted batch + bias (one block per graph) ----------------
__device__ inline int lower_bound_dev(const int* a, int n, int key) {
    int lo = 0, hi = n;
    while (lo < hi) {
        int mid = (lo + hi) >> 1;
        if (a[mid] < key) lo = mid + 1; else hi = mid;
    }
    return lo;
}

__global__ __launch_bounds__(256) void k_pool(const float* __restrict__ nodeS, const int* __restrict__ batch,
                                              const float* __restrict__ bfc, float* __restrict__ out) {
    int g = blockIdx.x;
    int t = threadIdx.x;
    int lo = lower_bound_dev(batch, N_NODES, g);
    int hi = lower_bound_dev(batch, N_NODES, g + 1);
    float s = 0.f;
    for (int i = lo + t; i < hi; i += 256) s += nodeS[i];
    for (int d = 32; d > 0; d >>= 1) s += __shfl_down(s, d, 64);
    __shared__ float ws[4];
    int lane = t & 63, w = t >> 6;
    if (lane == 0) ws[w] = s;
    __syncthreads();
    if (t == 0) {
        float tot = ws[0] + ws[1] + ws[2] + ws[3];
        float cnt = (float)(hi - lo);
        out[g] = tot / fmaxf(cnt, 1.0f) + bfc[0];
    }
}

// ---------------- launch ----------------
extern "C" void kernel_launch(void* const* d_in, const int* in_sizes, int n_in,
                              void* d_out, int out_size, void* d_ws, size_t ws_size,
                              hipStream_t stream) {
    const float* x    = (const float*)d_in[0];
    const int*   ei   = (const int*)d_in[1];     // [2, E] : row0 = src, row1 = dst
    const int*   batch= (const int*)d_in[2];
    const float* W1   = (const float*)d_in[3];
    const float* b1   = (const float*)d_in[4];
    const float* W2   = (const float*)d_in[5];
    const float* b2   = (const float*)d_in[6];
    const float* W3   = (const float*)d_in[7];
    const float* b3   = (const float*)d_in[8];
    const float* Wfc  = (const float*)d_in[9];
    const float* bfc  = (const float*)d_in[10];
    float* out = (float*)d_out;

    const int* src = ei;
    const int* dst = ei + N_EDGES;

    // carve workspace (256B-aligned)
    char* p = (char*)d_ws;
    auto carve = [&](size_t bytes) { void* r = (void*)p; p += (bytes + 255) & ~(size_t)255; return r; };
    int*    cur       = (int*)   carve(sizeof(int) * (size_t)NBUCK * NSUB * CURSTRIDE);   // 800 KB
    uint32* bbuf      = (uint32*)carve(sizeof(uint32) * (size_t)NBUCK * NSUB * SUBCAP);   // 12.8 MB
    int*    bucketBase= (int*)   carve(sizeof(int) * (NBUCK + 1));
    float*  dinv      = (float*) carve(sizeof(float) * N_NODES);
    int*    offsets   = (int*)   carve(sizeof(int) * (N_NODES + 1));
    int*    col       = (int*)   carve(sizeof(int) * N_EDGES);
    unsigned short* XW = (unsigned short*)carve(sizeof(short) * (size_t)N_NODES * NFEAT);
    unsigned short* H  = (unsigned short*)carve(sizeof(short) * (size_t)N_NODES * NFEAT);
    unsigned short* WT = (unsigned short*)carve(sizeof(short) * 3 * NFEAT * NFEAT);
    float* nodeS      = (float*) carve(sizeof(float) * N_NODES);

    const int edgeBlocks = (N_EDGES + 255) / 256;            // 6250
    const int waveNodeBlocks = (N_NODES * 64 + 255) / 256;   // 25000
    const int gemmBlocks = (N_NODES + 63) / 64;              // 1563

    hipMemsetAsync(cur, 0, sizeof(int) * (size_t)NBUCK * NSUB * CURSTRIDE, stream);
    k_scatter<<<edgeBlocks, 256, 0, stream>>>(src, dst, cur, bbuf);
    k_bucketscan<<<1, 256, 0, stream>>>(cur, bucketBase, offsets);
    k_build<<<NBUCK, 256, 0, stream>>>(bbuf, cur, bucketBase, col, offsets, dinv);

    k_castw<<<(3 * NFEAT * NFEAT + 255) / 256, 256, 0, stream>>>(W1, W2, W3, WT);

    // layer 1 (cast fused into GEMM A-load)
    k_gemm_x<<<gemmBlocks, 256, 0, stream>>>(x, WT, XW, N_NODES);
    k_agg<<<waveNodeBlocks, 256, 0, stream>>>((const uint32*)XW, col, offsets, dinv, b1, (uint32*)H);
    // layer 2
    k_gemm<<<gemmBlocks, 256, 0, stream>>>(H, WT + NFEAT * NFEAT, XW, N_NODES);
    k_agg<<<waveNodeBlocks, 256, 0, stream>>>((const uint32*)XW, col, offsets, dinv, b2, (uint32*)H);
    // layer 3
    k_gemm<<<gemmBlocks, 256, 0, stream>>>(H, WT + 2 * NFEAT * NFEAT, XW, N_NODES);
    k_agg_fc<<<waveNodeBlocks, 256, 0, stream>>>((const uint32*)XW, col, offsets, dinv, b3, Wfc, nodeS);

    k_pool<<<N_GRAPHS, 256, 0, stream>>>(nodeS, batch, bfc, out);
}